// Round 9
// baseline (1421.144 us; speedup 1.0000x reference)
//
#include <hip/hip_runtime.h>
#include <math.h>

// MS-SSIM loss, 5 levels, 11x11 separable Gaussian, zero padding.
// R9 = R5 (best verified: named-scalar ring, base-ptr+immediate tap loads,
// MASKED/interior template split) + one lever: tap loads software-pipelined
// ONE FULL ROW ahead via two named-scalar tap banks (E/O). Load->use distance
// becomes a whole row body (~340 cyc) instead of ~80, covering L2 latency.
// Ring widened to 12 slots so the runtime loop body is 12 rows (bank parity
// and slot indices stay compile-time; body ~17KB fits I-cache; 3 iters cover
// CH=32 with 4 tail rows dropped by a live guard).
// Scratch-proofing rules learned R4/R8: no arrays, no per-tap address regs.

#define NIMG 48            // 16 * 3
#define CH 32              // chunk height; divides 512,256,128,64,32
#define TWO_C1 2.0e-4f     // 2 * (0.01*1.0)^2
#define TWO_C2 1.8e-3f     // 2 * (0.03*1.0)^2

struct CInfo { int base[5]; int cnt[5]; };

#define FOR11(X) X(0) X(1) X(2) X(3) X(4) X(5) X(6) X(7) X(8) X(9) X(10)
#define FOR12(X) FOR11(X) X(11)
#define FOR11B(X,B) X(B,0) X(B,1) X(B,2) X(B,3) X(B,4) X(B,5) \
                    X(B,6) X(B,7) X(B,8) X(B,9) X(B,10)

#define DECLR(K) float rA##K = 0.f, rB##K = 0.f, rP##K = 0.f, rQ##K = 0.f;
#define TDECL(K) float pE##K = 0.f, tE##K = 0.f, pO##K = 0.f, tO##K = 0.f;

// Tap loads into bank B: ONE per-lane base pointer + immediate offsets
// (the R5 addressing form that stays scratch-free). Clamp math only in the
// MASKED template; OOB rows zero the bank (=> h-conv yields 0 = zero-pad).
#define LD_I(B,K) p##B##K = rpl_[K]; t##B##K = rtl_[K];
#define LD_M(B,K) { const int x_ = gx + (K) - 5; \
    const int xc_ = min(max(x_, 0), W - 1); \
    const float pv_ = rp_[xc_], tv_ = rt_[xc_]; \
    const bool ok_ = ((unsigned)x_ < (unsigned)W); \
    p##B##K = ok_ ? pv_ : 0.f; t##B##K = ok_ ? tv_ : 0.f; }
#define LD_Z(B,K) p##B##K = 0.f; t##B##K = 0.f;

#define LOADT(B, R) do { const int r_ = (R); \
    if ((unsigned)r_ < (unsigned)H) { \
      const float* rp_ = Pi + (size_t)r_ * W; \
      const float* rt_ = Ti + (size_t)r_ * W; \
      if (MASKED) { FOR11B(LD_M, B) } \
      else { const float* rpl_ = rp_ + gx - 5; \
             const float* rtl_ = rt_ + gx - 5; \
             FOR11B(LD_I, B) } \
    } else { FOR11B(LD_Z, B) } } while (0)

// Horizontal 11-tap conv of bank B -> ring slot SW (literal), plus fused
// 2x2 avg-pool bookkeeping on the bank's center taps (row R).
#define HA(B,K) { const float a_ = p##B##K + t##B##K, b_ = p##B##K - t##B##K; \
    hA_ = __builtin_fmaf(G##K, a_, hA_); \
    hB_ = __builtin_fmaf(G##K, b_, hB_); \
    hP_ = __builtin_fmaf(G##K * a_, a_, hP_); \
    hQ_ = __builtin_fmaf(G##K * b_, b_, hQ_); }

#define HCONV(B, SW, R) do { const int r_ = (R); \
    float hA_ = 0.f, hB_ = 0.f, hP_ = 0.f, hQ_ = 0.f; \
    FOR11B(HA, B) \
    rA##SW = hA_; rB##SW = hB_; rP##SW = hP_; rQ##SW = hQ_; \
    if (DS) { \
      if (r_ >= y0 && r_ < y0 + CH) { \
        if ((r_ & 1) == 0) { pr = p##B##5; tr = t##B##5; } \
        else { \
          float sp_ = pr + p##B##5, st_ = tr + t##B##5; \
          sp_ += __shfl_xor(sp_, 1, 64); \
          st_ += __shfl_xor(st_, 1, 64); \
          if (((lane & 1) == 0) && (gx < W)) { \
            const size_t o_ = obase + (size_t)(r_ >> 1) * (size_t)(W >> 1) + \
                              (size_t)(gx >> 1); \
            dsP[o_] = sp_ * 0.25f; \
            dsT[o_] = st_ * 0.25f; \
          } } } } } while (0)

#define VSTEP(GK, S) \
    vA_ = __builtin_fmaf(GK, rA##S, vA_); vB_ = __builtin_fmaf(GK, rB##S, vB_); \
    vP_ = __builtin_fmaf(GK, rP##S, vP_); vQ_ = __builtin_fmaf(GK, rQ##S, vQ_);

// One pipelined row: issue next row's loads into bank BL, h-conv current
// bank BC (loaded last row) into slot SW, v-conv slots S0..S9 + SW, stats.
#define ROWP(JJ, BL, BC, SW, S0,S1,S2,S3,S4,S5,S6,S7,S8,S9) do { \
    const int i_ = base + (JJ); \
    LOADT(BL, y0 + 6 + i_); \
    HCONV(BC, SW, y0 + 5 + i_); \
    float vA_ = G0 * rA##S0, vB_ = G0 * rB##S0; \
    float vP_ = G0 * rP##S0, vQ_ = G0 * rQ##S0; \
    VSTEP(G1, S1) VSTEP(G2, S2) VSTEP(G3, S3) VSTEP(G4, S4) VSTEP(G5, S5) \
    VSTEP(G6, S6) VSTEP(G7, S7) VSTEP(G8, S8) VSTEP(G9, S9) VSTEP(G10, SW) \
    const float A2_ = vA_ * vA_, B2_ = vB_ * vB_; \
    const float dAB_ = A2_ - B2_, sAB_ = A2_ + B2_; \
    const float cn_ = (vP_ - vQ_) - dAB_ + TWO_C2; \
    const float cd_ = (vP_ + vQ_) - sAB_ + TWO_C2; \
    float val_; \
    if (LAST) val_ = ((dAB_ + TWO_C1) * cn_) / ((sAB_ + TWO_C1) * cd_); \
    else      val_ = cn_ / cd_; \
    if ((i_ < CH) && (!MASKED || gx < W)) sum += val_; \
  } while (0)

template <int MASKED, int DS, int LAST>
__device__ __forceinline__ float strip_run(
    const float* __restrict__ Pi, const float* __restrict__ Ti,
    const int H, const int W, const int y0, const int c0,
    float* __restrict__ dsP, float* __restrict__ dsT, const size_t obase,
    const float G0, const float G1, const float G2, const float G3,
    const float G4, const float G5, const float G6, const float G7,
    const float G8, const float G9, const float G10) {
  const int lane = threadIdx.x & 63;
  const int gx = c0 + lane;
  FOR12(DECLR)          // ring slots 0..11, named scalars
  FOR11(TDECL)          // tap banks E/O, named scalars
  float pr = 0.f, tr = 0.f, sum = 0.f;

  // Prologue: fill slots 0..9 with rows y0-5..y0+4, banks alternating; ends
  // with bank E holding row y0+5 (consumed by main row 0).
  LOADT(E, y0 - 5);
  LOADT(O, y0 - 4); HCONV(E, 0, y0 - 5);
  LOADT(E, y0 - 3); HCONV(O, 1, y0 - 4);
  LOADT(O, y0 - 2); HCONV(E, 2, y0 - 3);
  LOADT(E, y0 - 1); HCONV(O, 3, y0 - 2);
  LOADT(O, y0 + 0); HCONV(E, 4, y0 - 1);
  LOADT(E, y0 + 1); HCONV(O, 5, y0 + 0);
  LOADT(O, y0 + 2); HCONV(E, 6, y0 + 1);
  LOADT(E, y0 + 3); HCONV(O, 7, y0 + 2);
  LOADT(O, y0 + 4); HCONV(E, 8, y0 + 3);
  LOADT(E, y0 + 5); HCONV(O, 9, y0 + 4);

  // Main: 12-row body (ring period 12 x bank period 2), 3 iterations cover
  // 32 output rows + 4 dead tail rows dropped by the i_<CH guard.
  for (int base = 0; base < CH; base += 12) {
    ROWP(0,  O, E, 10, 0,1,2,3,4,5,6,7,8,9);
    ROWP(1,  E, O, 11, 1,2,3,4,5,6,7,8,9,10);
    ROWP(2,  O, E, 0,  2,3,4,5,6,7,8,9,10,11);
    ROWP(3,  E, O, 1,  3,4,5,6,7,8,9,10,11,0);
    ROWP(4,  O, E, 2,  4,5,6,7,8,9,10,11,0,1);
    ROWP(5,  E, O, 3,  5,6,7,8,9,10,11,0,1,2);
    ROWP(6,  O, E, 4,  6,7,8,9,10,11,0,1,2,3);
    ROWP(7,  E, O, 5,  7,8,9,10,11,0,1,2,3,4);
    ROWP(8,  O, E, 6,  8,9,10,11,0,1,2,3,4,5);
    ROWP(9,  E, O, 7,  9,10,11,0,1,2,3,4,5,6);
    ROWP(10, O, E, 8,  10,11,0,1,2,3,4,5,6,7);
    ROWP(11, E, O, 9,  11,0,1,2,3,4,5,6,7,8);
  }
  return sum;
}

template <int DS, int LAST>
__global__ __launch_bounds__(256, 3)
void msssim_level_k(const float* __restrict__ P, const float* __restrict__ T,
                    const int H, const int W, const int strips,
                    const int chunks, const int tasks,
                    float* __restrict__ dsP, float* __restrict__ dsT,
                    double* __restrict__ partial,
                    const float G0, const float G1, const float G2,
                    const float G3, const float G4, const float G5,
                    const float G6, const float G7, const float G8,
                    const float G9, const float G10) {
  __shared__ float sRed[4];
  const int tid = threadIdx.x;
  const int lane = tid & 63;
  const int wid = tid >> 6;
  float sum = 0.f;
  const int task = blockIdx.x * 4 + wid;
  if (task < tasks) {
    const int strip = task % strips;
    const int rem = task / strips;
    const int chunk = rem % chunks;
    const int img = rem / chunks;
    const int y0 = chunk * CH;
    const size_t ibase = (size_t)img * H * W;
    const size_t obase = DS ? (size_t)img * (size_t)(H >> 1) * (W >> 1) : 0;
    const bool edge = (strip == 0) || (strip * 64 + 69 > W);  // wave-uniform
    if (edge)
      sum = strip_run<1, DS, LAST>(P + ibase, T + ibase, H, W, y0, strip * 64,
                                   dsP, dsT, obase,
                                   G0, G1, G2, G3, G4, G5, G6, G7, G8, G9, G10);
    else
      sum = strip_run<0, DS, LAST>(P + ibase, T + ibase, H, W, y0, strip * 64,
                                   dsP, dsT, obase,
                                   G0, G1, G2, G3, G4, G5, G6, G7, G8, G9, G10);
  }
#pragma unroll
  for (int off = 32; off; off >>= 1) sum += __shfl_down(sum, off, 64);
  if (lane == 0) sRed[wid] = sum;
  __syncthreads();
  if (tid == 0)
    partial[blockIdx.x] = (double)(sRed[0] + sRed[1] + sRed[2] + sRed[3]);
}

__global__ void msssim_combine_k(const double* __restrict__ partial,
                                 float* __restrict__ out, const CInfo ci) {
  const int lane = threadIdx.x & 63;
  double lv[5];
#pragma unroll
  for (int L = 0; L < 5; ++L) {
    double s = 0.0;
    for (int i = lane; i < ci.cnt[L]; i += 64) s += partial[ci.base[L] + i];
#pragma unroll
    for (int off = 32; off; off >>= 1) s += __shfl_down(s, off, 64);
    lv[L] = s;
  }
  if (lane == 0) {
    double ms = lv[4] / (48.0 * 32.0 * 32.0);
    ms *= pow(lv[0] / (48.0 * 512.0 * 512.0), (double)0.0448f);
    ms *= pow(lv[1] / (48.0 * 256.0 * 256.0), (double)0.2856f);
    ms *= pow(lv[2] / (48.0 * 128.0 * 128.0), (double)0.3001f);
    ms *= pow(lv[3] / (48.0 * 64.0 * 64.0),  (double)0.2363f);
    out[0] = (float)(1.0 - ms);
  }
}

extern "C" void kernel_launch(void* const* d_in, const int* in_sizes, int n_in,
                              void* d_out, int out_size, void* d_ws, size_t ws_size,
                              hipStream_t stream) {
  const float* pred = (const float*)d_in[0];
  const float* targ = (const float*)d_in[1];
  float* out = (float*)d_out;

  char* ws = (char*)d_ws;
  double* partial = (double*)ws;  // per-block partial sums, 32KB region
  size_t off = 32768;
  auto alloc = [&](size_t elems) {
    float* p = (float*)(ws + off);
    off += elems * sizeof(float);
    return p;
  };
  float* L1p = alloc((size_t)NIMG * 256 * 256);
  float* L1t = alloc((size_t)NIMG * 256 * 256);
  float* L2p = alloc((size_t)NIMG * 128 * 128);
  float* L2t = alloc((size_t)NIMG * 128 * 128);
  float* L3p = alloc((size_t)NIMG * 64 * 64);
  float* L3t = alloc((size_t)NIMG * 64 * 64);
  float* L4p = alloc((size_t)NIMG * 32 * 32);
  float* L4t = alloc((size_t)NIMG * 32 * 32);

  float g[11];
  {
    double gd[11], s = 0.0;
    for (int k = 0; k < 11; ++k) {
      const double c = (double)(k - 5);
      gd[k] = exp(-(c * c) / 4.5);  // 2*sigma^2 = 4.5
      s += gd[k];
    }
    for (int k = 0; k < 11; ++k) g[k] = (float)(gd[k] / s);
  }

  CInfo ci;
  int slotOff = 0;

  auto launchLevel = [&](const float* P, const float* T, int H, int W,
                         float* dP, float* dT, int L, bool last) {
    const int strips = (W + 63) / 64;
    const int chunks = H / CH;
    const int tasks = strips * chunks * NIMG;
    const int blocks = (tasks + 3) / 4;
    ci.base[L] = slotOff;
    ci.cnt[L] = blocks;
    if (last) {
      msssim_level_k<0, 1><<<blocks, 256, 0, stream>>>(
          P, T, H, W, strips, chunks, tasks, nullptr, nullptr,
          partial + slotOff, g[0], g[1], g[2], g[3], g[4], g[5], g[6], g[7],
          g[8], g[9], g[10]);
    } else {
      msssim_level_k<1, 0><<<blocks, 256, 0, stream>>>(
          P, T, H, W, strips, chunks, tasks, dP, dT,
          partial + slotOff, g[0], g[1], g[2], g[3], g[4], g[5], g[6], g[7],
          g[8], g[9], g[10]);
    }
    slotOff += blocks;
  };

  launchLevel(pred, targ, 512, 512, L1p, L1t, 0, false);
  launchLevel(L1p, L1t, 256, 256, L2p, L2t, 1, false);
  launchLevel(L2p, L2t, 128, 128, L3p, L3t, 2, false);
  launchLevel(L3p, L3t, 64, 64, L4p, L4t, 3, false);
  launchLevel(L4p, L4t, 32, 32, nullptr, nullptr, 4, true);

  msssim_combine_k<<<1, 64, 0, stream>>>(partial, out, ci);
}

// Round 10
// 387.563 us; speedup vs baseline: 3.6669x; 3.6669x over previous
//
#include <hip/hip_runtime.h>
#include <math.h>

// MS-SSIM loss, 5 levels, 11x11 separable Gaussian, zero padding.
// R10 = R5 (the only verified-fast structure: named-scalar ring, ephemeral
// per-row taps, MASKED/interior split) + two within-row levers:
//   (1) interior tap loads vectorized: dwordx4+dwordx4+dwordx2+dword per
//       tensor (8 VMEM/row instead of 22; multi-dword global loads need only
//       dword alignment);
//   (2) row body reordered: issue loads -> 40 v-conv FMAs over OLD ring
//       slots (pure-register latency cover) -> h-conv -> final VSTEP(G10).
// Scratch rule from R2/R4/R8/R9 post-mortems: only the 44-float ring is
// long-lived; all taps/addresses are ephemeral inside one row body.

#define NIMG 48            // 16 * 3
#define TWO_C1 2.0e-4f     // 2 * (0.01*1.0)^2
#define TWO_C2 1.8e-3f     // 2 * (0.03*1.0)^2

struct CInfo { int base[5]; int cnt[5]; };

typedef float f4v __attribute__((ext_vector_type(4), aligned(4)));
typedef float f2v __attribute__((ext_vector_type(2), aligned(4)));

#define FOR11(X) X(0) X(1) X(2) X(3) X(4) X(5) X(6) X(7) X(8) X(9) X(10)

#define DECLR(K) float rA##K = 0.f, rB##K = 0.f, rP##K = 0.f, rQ##K = 0.f;

#define TAPLOAD_M(K) { \
    const int x_ = gx + (K) - 5; \
    const int xc_ = min(max(x_, 0), W - 1); \
    const float pv_ = rp_[xc_], tv_ = rt_[xc_]; \
    const bool ok_ = ((unsigned)x_ < (unsigned)W); \
    p##K = ok_ ? pv_ : 0.f; t##K = ok_ ? tv_ : 0.f; }
#define TAPZERO(K) p##K = 0.f; t##K = 0.f;

// Declare + load this row's taps (ephemeral). Interior: 8 vector loads.
#define MS_LOAD(R) \
    const int r_ = (R); \
    float p0, p1, p2, p3, p4, p5, p6, p7, p8, p9, p10; \
    float t0, t1, t2, t3, t4, t5, t6, t7, t8, t9, t10; \
    if ((unsigned)r_ < (unsigned)H) { \
      const float* rp_ = Pi + (size_t)r_ * W; \
      const float* rt_ = Ti + (size_t)r_ * W; \
      if (MASKED) { \
        FOR11(TAPLOAD_M) \
      } else { \
        const float* rpl_ = rp_ + gx - 5; \
        const float* rtl_ = rt_ + gx - 5; \
        const f4v pa_ = *(const f4v*)(rpl_); \
        const f4v pb_ = *(const f4v*)(rpl_ + 4); \
        const f2v pc_ = *(const f2v*)(rpl_ + 8); \
        const float pd_ = rpl_[10]; \
        const f4v ta_ = *(const f4v*)(rtl_); \
        const f4v tb_ = *(const f4v*)(rtl_ + 4); \
        const f2v tc_ = *(const f2v*)(rtl_ + 8); \
        const float td_ = rtl_[10]; \
        p0 = pa_.x; p1 = pa_.y; p2 = pa_.z; p3 = pa_.w; \
        p4 = pb_.x; p5 = pb_.y; p6 = pb_.z; p7 = pb_.w; \
        p8 = pc_.x; p9 = pc_.y; p10 = pd_; \
        t0 = ta_.x; t1 = ta_.y; t2 = ta_.z; t3 = ta_.w; \
        t4 = tb_.x; t5 = tb_.y; t6 = tb_.z; t7 = tb_.w; \
        t8 = tc_.x; t9 = tc_.y; t10 = td_; \
      } \
    } else { FOR11(TAPZERO) }

#define HACC(K) { \
    const float a_ = p##K + t##K; \
    const float b_ = p##K - t##K; \
    hA_ = __builtin_fmaf(G##K, a_, hA_); \
    hB_ = __builtin_fmaf(G##K, b_, hB_); \
    hP_ = __builtin_fmaf(G##K * a_, a_, hP_); \
    hQ_ = __builtin_fmaf(G##K * b_, b_, hQ_); }

// H-conv this row's taps -> ring slot SW; fused 2x2 avg-pool on center taps.
#define MS_HC(SW) \
    float hA_ = 0.f, hB_ = 0.f, hP_ = 0.f, hQ_ = 0.f; \
    FOR11(HACC) \
    rA##SW = hA_; rB##SW = hB_; rP##SW = hP_; rQ##SW = hQ_; \
    if (DS) { \
      if (r_ >= y0 && r_ < y0 + nout) { \
        if ((r_ & 1) == 0) { pr = p5; tr = t5; } \
        else { \
          float sp_ = pr + p5, st_ = tr + t5; \
          sp_ += __shfl_xor(sp_, 1, 64); \
          st_ += __shfl_xor(st_, 1, 64); \
          if (((lane & 1) == 0) && (gx < W)) { \
            const size_t o_ = obase + (size_t)(r_ >> 1) * (size_t)(W >> 1) + \
                              (size_t)(gx >> 1); \
            dsP[o_] = sp_ * 0.25f; \
            dsT[o_] = st_ * 0.25f; \
          } } } }

#define VSTEP(GK, S) \
    vA_ = __builtin_fmaf(GK, rA##S, vA_); vB_ = __builtin_fmaf(GK, rB##S, vB_); \
    vP_ = __builtin_fmaf(GK, rP##S, vP_); vQ_ = __builtin_fmaf(GK, rQ##S, vQ_);

// Prologue row: fill ring slot SW (no v-conv).
#define PSTEP(R, SW) do { MS_LOAD(R) MS_HC(SW) } while (0)

// Output row IROW: loads -> 40-FMA v-conv over old slots S0..S9 (latency
// cover) -> h-conv into SW -> final tap VSTEP(G10, SW) -> stats.
#define ROW_N(IROW, SW, S0,S1,S2,S3,S4,S5,S6,S7,S8,S9) do { \
    const int i_ = (IROW); \
    const bool live_ = (i_ < nout); \
    MS_LOAD(y0 + 5 + i_) \
    float vA_ = G0 * rA##S0, vB_ = G0 * rB##S0; \
    float vP_ = G0 * rP##S0, vQ_ = G0 * rQ##S0; \
    VSTEP(G1, S1) VSTEP(G2, S2) VSTEP(G3, S3) VSTEP(G4, S4) VSTEP(G5, S5) \
    VSTEP(G6, S6) VSTEP(G7, S7) VSTEP(G8, S8) VSTEP(G9, S9) \
    MS_HC(SW) \
    VSTEP(G10, SW) \
    const float A2_ = vA_ * vA_, B2_ = vB_ * vB_; \
    const float dAB_ = A2_ - B2_, sAB_ = A2_ + B2_; \
    const float cn_ = (vP_ - vQ_) - dAB_ + TWO_C2; \
    const float cd_ = (vP_ + vQ_) - sAB_ + TWO_C2; \
    float val_; \
    if (LAST) val_ = ((dAB_ + TWO_C1) * cn_) / ((sAB_ + TWO_C1) * cd_); \
    else      val_ = cn_ / cd_; \
    if ((!MASKED || gx < W) && live_) sum += val_; \
  } while (0)

template <int MASKED, int DS, int LAST>
__device__ __forceinline__ float strip_run(
    const float* __restrict__ Pi, const float* __restrict__ Ti,
    const int H, const int W, const int y0, const int nout, const int c0,
    float* __restrict__ dsP, float* __restrict__ dsT, const size_t obase,
    const float G0, const float G1, const float G2, const float G3,
    const float G4, const float G5, const float G6, const float G7,
    const float G8, const float G9, const float G10) {
  const int lane = threadIdx.x & 63;
  const int gx = c0 + lane;
  FOR11(DECLR)                       // ring rA0..rQ10, named scalars
  float pr = 0.f, tr = 0.f, sum = 0.f;

  // Prologue: slots 0..9 <- rows y0-5 .. y0+4.
  PSTEP(y0 - 5, 0); PSTEP(y0 - 4, 1); PSTEP(y0 - 3, 2); PSTEP(y0 - 2, 3);
  PSTEP(y0 - 1, 4); PSTEP(y0 + 0, 5); PSTEP(y0 + 1, 6); PSTEP(y0 + 2, 7);
  PSTEP(y0 + 3, 8); PSTEP(y0 + 4, 9);

  // Main: 11 phases per iteration; slot lists rotate by one each phase.
  for (int base = 0; base < nout; base += 11) {
    ROW_N(base + 0, 10, 0,1,2,3,4,5,6,7,8,9);
    ROW_N(base + 1, 0,  1,2,3,4,5,6,7,8,9,10);
    ROW_N(base + 2, 1,  2,3,4,5,6,7,8,9,10,0);
    ROW_N(base + 3, 2,  3,4,5,6,7,8,9,10,0,1);
    ROW_N(base + 4, 3,  4,5,6,7,8,9,10,0,1,2);
    ROW_N(base + 5, 4,  5,6,7,8,9,10,0,1,2,3);
    ROW_N(base + 6, 5,  6,7,8,9,10,0,1,2,3,4);
    ROW_N(base + 7, 6,  7,8,9,10,0,1,2,3,4,5);
    ROW_N(base + 8, 7,  8,9,10,0,1,2,3,4,5,6);
    ROW_N(base + 9, 8,  9,10,0,1,2,3,4,5,6,7);
    ROW_N(base + 10, 9, 10,0,1,2,3,4,5,6,7,8);
  }
  return sum;
}

template <int DS, int LAST>
__global__ __launch_bounds__(256, 3)
void msssim_level_k(const float* __restrict__ P, const float* __restrict__ T,
                    const int H, const int W, const int strips,
                    const int chunks, const int chunkH, const int tasks,
                    float* __restrict__ dsP, float* __restrict__ dsT,
                    double* __restrict__ partial,
                    const float G0, const float G1, const float G2,
                    const float G3, const float G4, const float G5,
                    const float G6, const float G7, const float G8,
                    const float G9, const float G10) {
  __shared__ float sRed[4];
  const int tid = threadIdx.x;
  const int lane = tid & 63;
  const int wid = tid >> 6;
  float sum = 0.f;
  const int task = blockIdx.x * 4 + wid;
  if (task < tasks) {
    const int strip = task % strips;
    const int rem = task / strips;
    const int chunk = rem % chunks;
    const int img = rem / chunks;
    const int y0 = chunk * chunkH;
    const int nout = min(chunkH, H - y0);
    const size_t ibase = (size_t)img * H * W;
    const size_t obase = DS ? (size_t)img * (size_t)(H >> 1) * (W >> 1) : 0;
    const bool edge = (strip == 0) || (strip * 64 + 69 > W);  // wave-uniform
    if (edge)
      sum = strip_run<1, DS, LAST>(P + ibase, T + ibase, H, W, y0, nout,
                                   strip * 64, dsP, dsT, obase,
                                   G0, G1, G2, G3, G4, G5, G6, G7, G8, G9, G10);
    else
      sum = strip_run<0, DS, LAST>(P + ibase, T + ibase, H, W, y0, nout,
                                   strip * 64, dsP, dsT, obase,
                                   G0, G1, G2, G3, G4, G5, G6, G7, G8, G9, G10);
  }
#pragma unroll
  for (int off = 32; off; off >>= 1) sum += __shfl_down(sum, off, 64);
  if (lane == 0) sRed[wid] = sum;
  __syncthreads();
  if (tid == 0)
    partial[blockIdx.x] = (double)(sRed[0] + sRed[1] + sRed[2] + sRed[3]);
}

__global__ void msssim_combine_k(const double* __restrict__ partial,
                                 float* __restrict__ out, const CInfo ci) {
  const int lane = threadIdx.x & 63;
  double lv[5];
#pragma unroll
  for (int L = 0; L < 5; ++L) {
    double s = 0.0;
    for (int i = lane; i < ci.cnt[L]; i += 64) s += partial[ci.base[L] + i];
#pragma unroll
    for (int off = 32; off; off >>= 1) s += __shfl_down(s, off, 64);
    lv[L] = s;
  }
  if (lane == 0) {
    double ms = lv[4] / (48.0 * 32.0 * 32.0);
    ms *= pow(lv[0] / (48.0 * 512.0 * 512.0), (double)0.0448f);
    ms *= pow(lv[1] / (48.0 * 256.0 * 256.0), (double)0.2856f);
    ms *= pow(lv[2] / (48.0 * 128.0 * 128.0), (double)0.3001f);
    ms *= pow(lv[3] / (48.0 * 64.0 * 64.0),  (double)0.2363f);
    out[0] = (float)(1.0 - ms);
  }
}

extern "C" void kernel_launch(void* const* d_in, const int* in_sizes, int n_in,
                              void* d_out, int out_size, void* d_ws, size_t ws_size,
                              hipStream_t stream) {
  const float* pred = (const float*)d_in[0];
  const float* targ = (const float*)d_in[1];
  float* out = (float*)d_out;

  char* ws = (char*)d_ws;
  double* partial = (double*)ws;  // per-block partial sums, 32KB region
  size_t off = 32768;
  auto alloc = [&](size_t elems) {
    float* p = (float*)(ws + off);
    off += elems * sizeof(float);
    return p;
  };
  float* L1p = alloc((size_t)NIMG * 256 * 256);
  float* L1t = alloc((size_t)NIMG * 256 * 256);
  float* L2p = alloc((size_t)NIMG * 128 * 128);
  float* L2t = alloc((size_t)NIMG * 128 * 128);
  float* L3p = alloc((size_t)NIMG * 64 * 64);
  float* L3t = alloc((size_t)NIMG * 64 * 64);
  float* L4p = alloc((size_t)NIMG * 32 * 32);
  float* L4t = alloc((size_t)NIMG * 32 * 32);

  float g[11];
  {
    double gd[11], s = 0.0;
    for (int k = 0; k < 11; ++k) {
      const double c = (double)(k - 5);
      gd[k] = exp(-(c * c) / 4.5);  // 2*sigma^2 = 4.5
      s += gd[k];
    }
    for (int k = 0; k < 11; ++k) g[k] = (float)(gd[k] / s);
  }

  CInfo ci;
  int slotOff = 0;

  auto launchLevel = [&](const float* P, const float* T, int H, int W,
                         int chunkH, float* dP, float* dT, int L, bool last) {
    const int strips = (W + 63) / 64;
    const int chunks = (H + chunkH - 1) / chunkH;
    const int tasks = strips * chunks * NIMG;
    const int blocks = (tasks + 3) / 4;
    ci.base[L] = slotOff;
    ci.cnt[L] = blocks;
    if (last) {
      msssim_level_k<0, 1><<<blocks, 256, 0, stream>>>(
          P, T, H, W, strips, chunks, chunkH, tasks, nullptr, nullptr,
          partial + slotOff, g[0], g[1], g[2], g[3], g[4], g[5], g[6], g[7],
          g[8], g[9], g[10]);
    } else {
      msssim_level_k<1, 0><<<blocks, 256, 0, stream>>>(
          P, T, H, W, strips, chunks, chunkH, tasks, dP, dT,
          partial + slotOff, g[0], g[1], g[2], g[3], g[4], g[5], g[6], g[7],
          g[8], g[9], g[10]);
    }
    slotOff += blocks;
  };

  launchLevel(pred, targ, 512, 512, 32, L1p, L1t, 0, false);
  launchLevel(L1p, L1t, 256, 256, 32, L2p, L2t, 1, false);
  launchLevel(L2p, L2t, 128, 128, 32, L3p, L3t, 2, false);
  launchLevel(L3p, L3t, 64, 64, 16, L4p, L4t, 3, false);
  launchLevel(L4p, L4t, 32, 32, 8, nullptr, nullptr, 4, true);

  msssim_combine_k<<<1, 64, 0, stream>>>(partial, out, ci);
}